// Round 17
// baseline (3202.475 us; speedup 1.0000x reference)
//
#include <hip/hip_runtime.h>
#include <hip/hip_bf16.h>

#define BB_ 16
#define T_ 2048
#define DIN_ 64
#define D_ 512
#define DI_ 1024
#define N_ 16
#define DC_ 4
#define R_ 32
#define L_ 3
#define DOUT_ 128
#define CL_ 64               // scan chunk length
#define NCH_ (T_ / CL_)      // 32 chunks

typedef __attribute__((ext_vector_type(8))) _Float16 f16x8;
typedef __attribute__((ext_vector_type(4))) float f32x4;

__device__ __forceinline__ float silu_f(float x) { return x / (1.f + __expf(-x)); }

// fast branch-free softplus: log(1+e^t) = max(t,0) + log(1+e^-|t|)
__device__ __forceinline__ float softplus_f(float t) {
    return fmaxf(t, 0.f) + __logf(1.f + __expf(-fabsf(t)));
}

__device__ __forceinline__ unsigned short f2h(float f) {
    union { _Float16 h; unsigned short u; } c;
    c.h = (_Float16)f;   // RNE
    return c.u;
}

// async global->LDS 16B per lane; LDS dest must be lane-linear (tid*16B).
__device__ __forceinline__ void gload_lds16(const unsigned short* g,
                                            unsigned short* l) {
    __builtin_amdgcn_global_load_lds(
        (const __attribute__((address_space(1))) void*)g,
        (__attribute__((address_space(3))) void*)l, 16, 0, 0);
}

// decode scale from amax bits: s = 2^(11 - e), so s*amax lands in [2^11, 2^12)
__device__ __forceinline__ float decode_scale(unsigned int bits) {
    if (bits == 0u) return 1.f;
    const int E = (int)(bits >> 23) & 0xFF;
    return __uint_as_float((unsigned)(265 - E) << 23);
}

__device__ __forceinline__ uint4 pack8(float4 lo, float4 hi, float s) {
    union { uint4 u; unsigned short h[8]; } r;
    r.h[0] = f2h(lo.x * s); r.h[1] = f2h(lo.y * s);
    r.h[2] = f2h(lo.z * s); r.h[3] = f2h(lo.w * s);
    r.h[4] = f2h(hi.x * s); r.h[5] = f2h(hi.y * s);
    r.h[6] = f2h(hi.z * s); r.h[7] = f2h(hi.w * s);
    return r.u;
}

// regions: 0-2 Win[l] (262144 f4), 3-5 Wout[l] (131072), 6 Wo (16384),
// 7-9 Wx[l] (16384). slot == region.
__device__ __forceinline__ const float* wregion(
    int r, const float* Win, const float* Wout, const float* Wx,
    const float* Wo, size_t* n4)
{
    if (r < 3)       { *n4 = 262144; return Win  + (size_t)r * 1048576; }
    else if (r < 6)  { *n4 = 131072; return Wout + (size_t)(r - 3) * 524288; }
    else if (r == 6) { *n4 = 16384;  return Wo; }
    else             { *n4 = 16384;  return Wx  + (size_t)(r - 7) * 65536; }
}

__global__ __launch_bounds__(256) void amax_all(
    const float* __restrict__ Win, const float* __restrict__ Wout,
    const float* __restrict__ Wx, const float* __restrict__ Wo,
    unsigned int* __restrict__ scales)
{
    size_t n4;
    const float* p = wregion(blockIdx.z, Win, Wout, Wx, Wo, &n4);
    float m = 0.f;
    for (size_t i = (size_t)blockIdx.x * 256 + threadIdx.x; i < n4;
         i += (size_t)gridDim.x * 256) {
        const float4 v = ((const float4*)p)[i];
        m = fmaxf(m, fmaxf(fmaxf(fabsf(v.x), fabsf(v.y)),
                           fmaxf(fabsf(v.z), fabsf(v.w))));
    }
#pragma unroll
    for (int off = 32; off; off >>= 1) m = fmaxf(m, __shfl_down(m, off));
    __shared__ float sm[4];
    if ((threadIdx.x & 63) == 0) sm[threadIdx.x >> 6] = m;
    __syncthreads();
    if (threadIdx.x == 0) {
        const float b = fmaxf(fmaxf(sm[0], sm[1]), fmaxf(sm[2], sm[3]));
        atomicMax(scales + blockIdx.z, __float_as_uint(b));
    }
}

__global__ __launch_bounds__(256) void cast_all(
    const float* __restrict__ Win, const float* __restrict__ Wout,
    const float* __restrict__ Wx, const float* __restrict__ Wo,
    unsigned short* __restrict__ WinH, unsigned short* __restrict__ WoutH,
    unsigned short* __restrict__ WxH, unsigned short* __restrict__ WoH,
    const unsigned int* __restrict__ scales)
{
    const int r = blockIdx.z;
    size_t n4;
    const float* p = wregion(r, Win, Wout, Wx, Wo, &n4);
    unsigned short* o;
    if (r < 3)       o = WinH  + (size_t)r * 1048576;
    else if (r < 6)  o = WoutH + (size_t)(r - 3) * 524288;
    else if (r == 6) o = WoH;
    else             o = WxH   + (size_t)(r - 7) * 65536;
    const float s = decode_scale(scales[r]);
    for (size_t i = (size_t)blockIdx.x * 256 + threadIdx.x; i < n4;
         i += (size_t)gridDim.x * 256) {
        const float4 v = ((const float4*)p)[i];
        ((ushort4*)o)[i] = make_ushort4(f2h(v.x * s), f2h(v.y * s),
                                        f2h(v.z * s), f2h(v.w * s));
    }
}

// tiny: u amax upper bound = max_c(|cb|+Sum|w|*amax_xz). 1 block.
__global__ __launch_bounds__(256) void ubound_kernel(
    const float* __restrict__ cw, const float* __restrict__ cb,
    const unsigned int* __restrict__ xzslot, unsigned int* __restrict__ uslot)
{
    const float amx = __uint_as_float(*xzslot);
    float m = 0.f;
    for (int c = threadIdx.x; c < DI_; c += 256) {
        const float4 w = *(const float4*)(cw + (size_t)c * 4);
        const float sw = fabsf(w.x) + fabsf(w.y) + fabsf(w.z) + fabsf(w.w);
        m = fmaxf(m, fabsf(cb[c]) + sw * amx);
    }
#pragma unroll
    for (int off = 32; off; off >>= 1) m = fmaxf(m, __shfl_down(m, off));
    __shared__ float sm[4];
    if ((threadIdx.x & 63) == 0) sm[threadIdx.x >> 6] = m;
    __syncthreads();
    if (threadIdx.x == 0) {
        const float b = fmaxf(fmaxf(sm[0], sm[1]), fmaxf(sm[2], sm[3]));
        atomicMax(uslot, __float_as_uint(b));
    }
}

// ------- scaled MFMA GEMM, A fp32 (cast during LDS staging), B f16 --------
// 128x128 tile, BK=32, 4 waves (2x2), per-wave 64x64 = 4x4 frags of 16x16x32.
// A: reg-prefetch pipeline. B: async global_load_lds, double-buffered.
// ACT: 0 = none, 3 = +bias tanh. Output fp32 (+ optional amax).
// NOTE: C must NOT alias A.
template<int ACT>
__global__ __launch_bounds__(256) void gemm_f32a_t128(
    const float* __restrict__ A, int lda,
    const unsigned short* __restrict__ B, int ldb,
    const float* __restrict__ bias,
    float* __restrict__ C, int ldc, int K,
    const unsigned int* __restrict__ sa, const unsigned int* __restrict__ sb,
    unsigned int* __restrict__ oamax)
{
    __shared__ __align__(16) unsigned short As[128 * 32];
    __shared__ __align__(16) unsigned short Bs[2][128 * 32];
    const int tid  = threadIdx.x;
    const int lane = tid & 63;
    const int w    = tid >> 6;
    const int wr   = (w >> 1) << 6;
    const int wc   = (w & 1) << 6;
    const int l15  = lane & 15, l4 = lane >> 4;
    const int row0 = blockIdx.y << 7, col0 = blockIdx.x << 7;
    const int tq   = tid >> 2;
    const int tr   = (tid & 3) << 3;

    const float sA  = decode_scale(*sa);
    const float inv = (1.f / sA) * (1.f / decode_scale(*sb));

    const float* Ar0 = A + (size_t)(row0 + tq) * lda + tr;
    const float* Ar1 = A + (size_t)(row0 + 64 + tq) * lda + tr;
    const unsigned short* Br0 = B + (size_t)(col0 + tq) * ldb + tr;
    const unsigned short* Br1 = B + (size_t)(col0 + 64 + tq) * ldb + tr;

    f32x4 acc[4][4];
#pragma unroll
    for (int m = 0; m < 4; ++m)
#pragma unroll
        for (int n = 0; n < 4; ++n) acc[m][n] = (f32x4){0.f, 0.f, 0.f, 0.f};

    float4 a0lo = *(const float4*)(Ar0), a0hi = *(const float4*)(Ar0 + 4);
    float4 a1lo = *(const float4*)(Ar1), a1hi = *(const float4*)(Ar1 + 4);
    gload_lds16(Br0, &Bs[0][tq * 32 + tr]);
    gload_lds16(Br1, &Bs[0][(64 + tq) * 32 + tr]);

    int cur = 0;
    for (int k0 = 0; k0 < K; k0 += 32) {
        __syncthreads();
        *(uint4*)&As[tq * 32 + tr]        = pack8(a0lo, a0hi, sA);
        *(uint4*)&As[(64 + tq) * 32 + tr] = pack8(a1lo, a1hi, sA);
        __syncthreads();

        if (k0 + 32 < K) {
            gload_lds16(Br0 + k0 + 32, &Bs[cur ^ 1][tq * 32 + tr]);
            gload_lds16(Br1 + k0 + 32, &Bs[cur ^ 1][(64 + tq) * 32 + tr]);
            a0lo = *(const float4*)(Ar0 + k0 + 32);
            a0hi = *(const float4*)(Ar0 + k0 + 36);
            a1lo = *(const float4*)(Ar1 + k0 + 32);
            a1hi = *(const float4*)(Ar1 + k0 + 36);
        }

        f16x8 af[4], bfr[4];
#pragma unroll
        for (int m = 0; m < 4; ++m)
            af[m] = *(const f16x8*)&As[(wr + m * 16 + l15) * 32 + l4 * 8];
#pragma unroll
        for (int n = 0; n < 4; ++n)
            bfr[n] = *(const f16x8*)&Bs[cur][(wc + n * 16 + l15) * 32 + l4 * 8];
#pragma unroll
        for (int m = 0; m < 4; ++m)
#pragma unroll
            for (int n = 0; n < 4; ++n)
                acc[m][n] = __builtin_amdgcn_mfma_f32_16x16x32_f16(
                    af[m], bfr[n], acc[m][n], 0, 0, 0);
        cur ^= 1;
    }

    float am = 0.f;
#pragma unroll
    for (int n = 0; n < 4; ++n) {
        const int col = col0 + wc + n * 16 + l15;
        float bc = 0.f;
        if (ACT == 3) bc = bias[col];
#pragma unroll
        for (int m = 0; m < 4; ++m) {
            const int rowb = row0 + wr + m * 16 + (l4 << 2);
#pragma unroll
            for (int r = 0; r < 4; ++r) {
                float v = acc[m][n][r] * inv;
                if (ACT == 3) v = tanhf(v + bc);
                C[(size_t)(rowb + r) * ldc + col] = v;
                am = fmaxf(am, fabsf(v));
            }
        }
    }
    if (oamax) {
#pragma unroll
        for (int off = 32; off; off >>= 1) am = fmaxf(am, __shfl_down(am, off));
        if (lane == 0) atomicMax(oamax, __float_as_uint(am));
    }
}

// conv+silu for 8 channels of row m (causal, per-channel weights), scaled f16.
__device__ __forceinline__ uint4 conv_row8(
    const float* __restrict__ xz, int m, int c0,
    const float* __restrict__ cw, const float* __restrict__ cb, float s)
{
    const int t = m & (T_ - 1);
    const float* xr = xz + (size_t)m * 2048 + c0;
    float x[4][8];
#pragma unroll
    for (int k = 0; k < 4; ++k) {
        const int dt = 3 - k;                 // rows m-3, m-2, m-1, m
        if (t >= dt) {
            *(float4*)&x[k][0] = *(const float4*)(xr - (size_t)dt * 2048);
            *(float4*)&x[k][4] = *(const float4*)(xr - (size_t)dt * 2048 + 4);
        } else {
#pragma unroll
            for (int j = 0; j < 8; ++j) x[k][j] = 0.f;
        }
    }
    union { uint4 u; unsigned short h[8]; } r;
#pragma unroll
    for (int j = 0; j < 8; ++j) {
        const int c = c0 + j;
        const float4 w = *(const float4*)(cw + (size_t)c * 4);
        float cv = cb[c];
        cv = fmaf(x[0][j], w.x, cv);
        cv = fmaf(x[1][j], w.y, cv);
        cv = fmaf(x[2][j], w.z, cv);
        cv = fmaf(x[3][j], w.w, cv);
        r.h[j] = f2h(silu_f(cv) * s);
    }
    return r.u;
}

// ---- dbc GEMM with fused conv: A = silu(dwconv(xin))=u computed in staging.
// A source = xz (ld 2048, cols 0..1023). B f16 Wx. 128x64 tile.
__global__ __launch_bounds__(256) void gemm_conv_t64n(
    const float* __restrict__ xz,
    const unsigned short* __restrict__ B, int ldb,
    const float* __restrict__ cw, const float* __restrict__ cb,
    float* __restrict__ C, int ldc, int K,
    const unsigned int* __restrict__ su, const unsigned int* __restrict__ sb)
{
    __shared__ __align__(16) unsigned short As[128 * 32];
    __shared__ __align__(16) unsigned short Bs[64 * 32];
    const int tid  = threadIdx.x;
    const int lane = tid & 63;
    const int w    = tid >> 6;
    const int l15  = lane & 15, l4 = lane >> 4;
    const int row0 = blockIdx.y << 7;
    const int tq   = tid >> 2;
    const int tr   = (tid & 3) << 3;

    const float sU  = decode_scale(*su);
    const float inv = (1.f / sU) * (1.f / decode_scale(*sb));

    const unsigned short* Br = B + (size_t)tq * ldb + tr;   // 64 rows

    f32x4 acc[2][4];
#pragma unroll
    for (int m = 0; m < 2; ++m)
#pragma unroll
        for (int n = 0; n < 4; ++n) acc[m][n] = (f32x4){0.f, 0.f, 0.f, 0.f};

    uint4 bv = *(const uint4*)(Br);

    for (int k0 = 0; k0 < K; k0 += 32) {
        const uint4 a0 = conv_row8(xz, row0 + tq, k0 + tr, cw, cb, sU);
        const uint4 a1 = conv_row8(xz, row0 + 64 + tq, k0 + tr, cw, cb, sU);
        __syncthreads();
        *(uint4*)&As[tq * 32 + tr]        = a0;
        *(uint4*)&As[(64 + tq) * 32 + tr] = a1;
        *(uint4*)&Bs[tq * 32 + tr]        = bv;
        __syncthreads();

        if (k0 + 32 < K) bv = *(const uint4*)(Br + k0 + 32);

        f16x8 af[2], bfr[4];
#pragma unroll
        for (int m = 0; m < 2; ++m)
            af[m] = *(const f16x8*)&As[(w * 32 + m * 16 + l15) * 32 + l4 * 8];
#pragma unroll
        for (int n = 0; n < 4; ++n)
            bfr[n] = *(const f16x8*)&Bs[(n * 16 + l15) * 32 + l4 * 8];
#pragma unroll
        for (int m = 0; m < 2; ++m)
#pragma unroll
            for (int n = 0; n < 4; ++n)
                acc[m][n] = __builtin_amdgcn_mfma_f32_16x16x32_f16(
                    af[m], bfr[n], acc[m][n], 0, 0, 0);
    }

#pragma unroll
    for (int n = 0; n < 4; ++n) {
        const int col = n * 16 + l15;
#pragma unroll
        for (int m = 0; m < 2; ++m) {
            const int rowb = row0 + w * 32 + m * 16 + (l4 << 2);
#pragma unroll
            for (int r = 0; r < 4; ++r)
                C[(size_t)(rowb + r) * ldc + col] = acc[m][n][r] * inv;
        }
    }
}

// ---------------- fp32 vector GEMM (input projection, K=64) ----------------
__global__ __launch_bounds__(256) void gemm_in(
    const float* __restrict__ A, int lda,
    const float* __restrict__ B, int ldb,
    const float* __restrict__ bias,
    float* __restrict__ C, int ldc, int K,
    unsigned int* __restrict__ oamax)
{
    __shared__ __align__(16) float As[8][128];
    __shared__ __align__(16) float Bs[8][128];
    const int tid  = threadIdx.x;
    const int row0 = blockIdx.y << 7;
    const int col0 = blockIdx.x << 7;
    const int tx = tid & 15, ty = tid >> 4;

    float acc[8][8];
#pragma unroll
    for (int i = 0; i < 8; ++i)
#pragma unroll
        for (int j = 0; j < 8; ++j) acc[i][j] = 0.f;

    const int arow = tid >> 1;
    const int acol = (tid & 1) << 2;
    const float* Ap = A + (size_t)(row0 + arow) * lda + acol;
    const float* Bp = B + (size_t)(col0 + arow) * ldb + acol;

    for (int k0 = 0; k0 < K; k0 += 8) {
        const float4 av = *(const float4*)(Ap + k0);
        const float4 bv = *(const float4*)(Bp + k0);
        __syncthreads();
        As[acol + 0][arow] = av.x; As[acol + 1][arow] = av.y;
        As[acol + 2][arow] = av.z; As[acol + 3][arow] = av.w;
        Bs[acol + 0][arow] = bv.x; Bs[acol + 1][arow] = bv.y;
        Bs[acol + 2][arow] = bv.z; Bs[acol + 3][arow] = bv.w;
        __syncthreads();
#pragma unroll
        for (int k = 0; k < 8; ++k) {
            float a[8], b[8];
            *(float4*)&a[0] = *(const float4*)&As[k][ty << 3];
            *(float4*)&a[4] = *(const float4*)&As[k][(ty << 3) + 4];
            *(float4*)&b[0] = *(const float4*)&Bs[k][tx << 3];
            *(float4*)&b[4] = *(const float4*)&Bs[k][(tx << 3) + 4];
#pragma unroll
            for (int i = 0; i < 8; ++i)
#pragma unroll
                for (int j = 0; j < 8; ++j)
                    acc[i][j] = fmaf(a[i], b[j], acc[i][j]);
        }
    }

    float bv8[8];
#pragma unroll
    for (int j = 0; j < 8; ++j) bv8[j] = bias[col0 + (tx << 3) + j];

    float am = 0.f;
#pragma unroll
    for (int i = 0; i < 8; ++i) {
        float v[8];
#pragma unroll
        for (int j = 0; j < 8; ++j) {
            v[j] = acc[i][j] + bv8[j];
            am = fmaxf(am, fabsf(v[j]));
        }
        float* Cp = C + (size_t)(row0 + (ty << 3) + i) * ldc + col0 + (tx << 3);
        *(float4*)(Cp)     = make_float4(v[0], v[1], v[2], v[3]);
        *(float4*)(Cp + 4) = make_float4(v[4], v[5], v[6], v[7]);
    }
#pragma unroll
    for (int off = 32; off; off >>= 1) am = fmaxf(am, __shfl_down(am, off));
    if ((tid & 63) == 0) atomicMax(oamax, __float_as_uint(am));
}

// -------- chunk-parallel selective scan, delta+conv fused (3 phases) ------
// u computed inline via 3-deep shift register (causal dwconv + silu).
// delta inline: dl = softplus(dot32(dbc[m,0:32], Wdt[d,:]) + bdt[d]).
// Fast path: a2[n] == (n+1)*a2[0] -> one exp2/step. P via exp2(a2[n]*sum(dl)).

__device__ __forceinline__ bool geo_check(const float* a2) {
    bool ok = true;
#pragma unroll
    for (int n = 1; n < N_; ++n)
        ok = ok && (fabsf(a2[n] - a2[0] * (n + 1)) <=
                    1e-5f * fmaxf(1.f, fabsf(a2[n])));
    return ok;
}

__global__ __launch_bounds__(256) void scan_pass1(
    const float* __restrict__ xz, const float* __restrict__ dbc,
    const float* __restrict__ A_log_l, const float* __restrict__ Wdt_l,
    const float* __restrict__ bdt_l, const float* __restrict__ cw_l,
    const float* __restrict__ cb_l,
    float* __restrict__ P, float* __restrict__ S)
{
    __shared__ __align__(16) float sAll[CL_][64];
    const int tid = threadIdx.x;
    const int b = blockIdx.x, ch = blockIdx.z;
    const int d = (blockIdx.y << 8) + tid;

    float a2[N_], hs[N_];
#pragma unroll
    for (int n = 0; n < N_; ++n) {
        a2[n] = -__expf(A_log_l[d * N_ + n]) * 1.44269504f;
        hs[n] = 0.f;
    }
    const bool geo = geo_check(a2);
    float wdt[32];
#pragma unroll
    for (int k = 0; k < 32; k += 4)
        *(float4*)&wdt[k] = *(const float4*)(Wdt_l + (size_t)d * 32 + k);
    const float bdt_d = bdt_l[d];
    const float4 cwv = *(const float4*)(cw_l + (size_t)d * 4);
    const float cbd = cb_l[d];

    const size_t mB = (size_t)b * T_ + (size_t)ch * CL_;
    const int t0 = ch * CL_;
    float xm1 = (t0 >= 1) ? xz[(mB - 1) * 2048 + d] : 0.f;
    float xm2 = (t0 >= 2) ? xz[(mB - 2) * 2048 + d] : 0.f;
    float xm3 = (t0 >= 3) ? xz[(mB - 3) * 2048 + d] : 0.f;

    const size_t base64 = mB * 64;
    float* sflat = &sAll[0][0];
    for (int i = tid; i < CL_ * 64; i += 256) sflat[i] = dbc[base64 + i];
    __syncthreads();

    float sdl = 0.f;
    for (int tt = 0; tt < CL_; ++tt) {
        float t = bdt_d;
#pragma unroll
        for (int k = 0; k < 32; k += 4) {
            const float4 dv = *(const float4*)&sAll[tt][k];
            t = fmaf(dv.x, wdt[k + 0], t);
            t = fmaf(dv.y, wdt[k + 1], t);
            t = fmaf(dv.z, wdt[k + 2], t);
            t = fmaf(dv.w, wdt[k + 3], t);
        }
        const float dl = softplus_f(t);
        sdl += dl;
        const size_t m = mB + tt;
        const float xc = xz[m * 2048 + d];
        float cv = fmaf(xc, cwv.w, fmaf(xm1, cwv.z,
                    fmaf(xm2, cwv.y, fmaf(xm3, cwv.x, cbd))));
        const float du = dl * silu_f(cv);
        xm3 = xm2; xm2 = xm1; xm1 = xc;
        if (geo) {
            const float r = exp2f(dl * a2[0]);
            float dA = r;
#pragma unroll
            for (int n = 0; n < N_; ++n) {
                hs[n] = fmaf(dA, hs[n], du * sAll[tt][32 + n]);
                dA *= r;
            }
        } else {
#pragma unroll
            for (int n = 0; n < N_; ++n) {
                const float dA = exp2f(dl * a2[n]);
                hs[n] = fmaf(dA, hs[n], du * sAll[tt][32 + n]);
            }
        }
    }
#pragma unroll
    for (int n = 0; n < N_; ++n) {
        const size_t idx = (size_t)(((b * NCH_ + ch) * N_ + n) << 10) + d;
        P[idx] = exp2f(sdl * a2[n]);
        S[idx] = hs[n];
    }
}

__global__ __launch_bounds__(256) void scan_carry(
    const float* __restrict__ P, float* __restrict__ S)
{
    const size_t gid = (size_t)blockIdx.x * 256 + threadIdx.x;
    const int d = (int)(gid & 1023);
    const int n = (int)((gid >> 10) & 15);
    const int b = (int)(gid >> 14);
    float hc = 0.f;
    for (int ch = 0; ch < NCH_; ++ch) {
        const size_t idx = (size_t)(((b * NCH_ + ch) * N_ + n) << 10) + d;
        const float p = P[idx], s = S[idx];
        S[idx] = hc;
        hc = fmaf(p, hc, s);
    }
}

__global__ __launch_bounds__(256) void scan_pass3(
    const float* __restrict__ xz, float* __restrict__ g,
    const float* __restrict__ dbc, const float* __restrict__ A_log_l,
    const float* __restrict__ Wdt_l, const float* __restrict__ bdt_l,
    const float* __restrict__ cw_l, const float* __restrict__ cb_l,
    const float* __restrict__ Dp_l, const float* __restrict__ S,
    unsigned int* __restrict__ gmax)
{
    __shared__ __align__(16) float sAll[CL_][64];
    const int tid = threadIdx.x;
    const int b = blockIdx.x, ch = blockIdx.z;
    const int d = (blockIdx.y << 8) + tid;

    float a2[N_], hs[N_];
#pragma unroll
    for (int n = 0; n < N_; ++n) {
        a2[n] = -__expf(A_log_l[d * N_ + n]) * 1.44269504f;
        hs[n] = S[(size_t)(((b * NCH_ + ch) * N_ + n) << 10) + d];
    }
    const bool geo = geo_check(a2);
    float wdt[32];
#pragma unroll
    for (int k = 0; k < 32; k += 4)
        *(float4*)&wdt[k] = *(const float4*)(Wdt_l + (size_t)d * 32 + k);
    const float bdt_d = bdt_l[d];
    const float4 cwv = *(const float4*)(cw_l + (size_t)d * 4);
    const float cbd = cb_l[d];
    const float Dpd = Dp_l[d];

    const size_t mB = (size_t)b * T_ + (size_t)ch * CL_;
    const int t0 = ch * CL_;
    float xm1 = (t0 >= 1) ? xz[(mB - 1) * 2048 + d] : 0.f;
    float xm2 = (t0 >= 2) ? xz[(mB - 2) * 2048 + d] : 0.f;
    float xm3 = (t0 >= 3) ? xz[(mB - 3) * 2048 + d] : 0.f;

    const size_t base64 = mB * 64;
    float* sflat = &sAll[0][0];
    for (int i = tid; i < CL_ * 64; i += 256) sflat[i] = dbc[base64 + i];
    __syncthreads();

    float gm = 0.f;
    for (int tt = 0; tt < CL_; ++tt) {
        float t = bdt_d;
#pragma unroll
        for (int k = 0; k < 32; k += 4) {
            const float4 dv = *(const float4*)&sAll[tt][k];
            t = fmaf(dv.x, wdt[k + 0], t);
            t = fmaf(dv.y, wdt[k + 1], t);
            t = fmaf(dv.z, wdt[k + 2], t);
            t = fmaf(dv.w, wdt[k + 3], t);
        }
        const float dl = softplus_f(t);
        const size_t m = mB + tt;
        const float xc = xz[m * 2048 + d];
        float cv = fmaf(xc, cwv.w, fmaf(xm1, cwv.z,
                    fmaf(xm2, cwv.y, fmaf(xm3, cwv.x, cbd))));
        const float uv = silu_f(cv);
        const float du = dl * uv;
        xm3 = xm2; xm2 = xm1; xm1 = xc;
        float yv = 0.f;
        if (geo) {
            const float r = exp2f(dl * a2[0]);
            float dA = r;
#pragma unroll
            for (int n = 0; n < N_; ++n) {
                hs[n] = fmaf(dA, hs[n], du * sAll[tt][32 + n]);
                yv = fmaf(hs[n], sAll[tt][48 + n], yv);
                dA *= r;
            }
        } else {
#pragma unroll
            for (int n = 0; n < N_; ++n) {
                const float dA = exp2f(dl * a2[n]);
                hs[n] = fmaf(dA, hs[n], du * sAll[tt][32 + n]);
                yv = fmaf(hs[n], sAll[tt][48 + n], yv);
            }
        }
        yv = fmaf(uv, Dpd, yv);
        const float gv = yv * silu_f(xz[m * 2048 + DI_ + d]);
        g[m * DI_ + d] = gv;
        gm = fmaxf(gm, fabsf(gv));
    }
#pragma unroll
    for (int off = 32; off; off >>= 1) gm = fmaxf(gm, __shfl_down(gm, off));
    if ((tid & 63) == 0) atomicMax(gmax, __float_as_uint(gm));
}

extern "C" void kernel_launch(void* const* d_in, const int* in_sizes, int n_in,
                              void* d_out, int out_size, void* d_ws, size_t ws_size,
                              hipStream_t stream) {
    const float* x     = (const float*)d_in[0];
    const float* Wi    = (const float*)d_in[1];
    const float* bi    = (const float*)d_in[2];
    const float* Win   = (const float*)d_in[3];
    const float* convw = (const float*)d_in[4];
    const float* convb = (const float*)d_in[5];
    const float* Wx    = (const float*)d_in[6];
    const float* Wdt   = (const float*)d_in[7];
    const float* bdt   = (const float*)d_in[8];
    const float* A_log = (const float*)d_in[9];
    const float* Dp    = (const float*)d_in[10];
    const float* Wout  = (const float*)d_in[11];
    const float* Wo    = (const float*)d_in[12];
    const float* bo    = (const float*)d_in[13];
    float* out = (float*)d_out;

    // Per-row f32: xz 2048 + gbuf 1024 + dbc 64 + hPS 512 (h | scan P,S) = 3648.
    const size_t rowf = 3648;
    const size_t wextra =
        (3 * 1048576 + 3 * 524288 + 65536 + 3 * 65536) / 2 + 32;
    int CB = BB_;
    while (CB > 1 && ((size_t)CB * T_ * rowf + wextra) * sizeof(float) > ws_size) CB >>= 1;
    const size_t Mc = (size_t)CB * T_;

    const dim3 blk(256);
    const int rowTiles = (int)(Mc / 128);

    float* ws   = (float*)d_ws;
    float* xz   = ws;                    // Mc*2048 (xin | z), never overwritten mid-layer
    float* gbuf = xz + Mc * 2048;        // Mc*1024 (g, was u)
    float* dbc  = gbuf + Mc * 1024;      // Mc*64
    float* hPS  = dbc + Mc * 64;         // Mc*512: h (ld 512) / scan P,S
    float* hb   = hPS;
    float* Pbuf = hPS;                               // CB*NCH*N*DI floats
    float* Sbuf = hPS + (size_t)CB * NCH_ * N_ * DI_;
    unsigned short* WinH  = (unsigned short*)(hPS + Mc * 512);
    unsigned short* WoutH = WinH + 3 * 1048576;
    unsigned short* WoH   = WoutH + 3 * 524288;
    unsigned short* WxH   = WoH + 65536;
    unsigned int* scales  = (unsigned int*)(WxH + 3 * 65536);
    // slots: 0-2 Win, 3-5 Wout, 6 Wo, 7-9 Wx,
    //        10..13 h[0..3], 14-16 g[l], 17-19 xzamax[l], 20-22 ubound[l]

    hipMemsetAsync(scales, 0, 32 * sizeof(unsigned int), stream);

    amax_all<<<dim3(128, 1, 10), blk, 0, stream>>>(Win, Wout, Wx, Wo, scales);
    cast_all<<<dim3(64, 1, 10), blk, 0, stream>>>(
        Win, Wout, Wx, Wo, WinH, WoutH, WxH, WoH, scales);

    for (int c = 0; c < BB_ / CB; ++c) {
        const float* x_c = x + (size_t)c * Mc * DIN_;
        float* out_c     = out + (size_t)c * Mc * DOUT_;

        hipMemsetAsync(scales + 10, 0, 16 * sizeof(unsigned int), stream);

        // h = x @ Wi.T + bi  (fp32, K=64) -> hb (ld 512), amax -> h[0]
        gemm_in<<<dim3(D_ / 128, rowTiles), blk, 0, stream>>>(
            x_c, DIN_, Wi, DIN_, bi, hb, D_, DIN_, scales + 10);

        for (int l = 0; l < L_; ++l) {
            const float* cw_l   = convw + (size_t)l * DI_ * DC_;
            const float* cb_l   = convb + (size_t)l * DI_;
            const float* Wdt_l  = Wdt  + (size_t)l * DI_ * R_;
            const float* bdt_l  = bdt  + (size_t)l * DI_;
            const float* Alog_l = A_log + (size_t)l * DI_ * N_;
            const float* Dp_l   = Dp   + (size_t)l * DI_;

            // xz = h @ Win.T  (A fp32 staged-cast, B async-lds); amax(xz)
            gemm_f32a_t128<0><<<dim3(2048 / 128, rowTiles), blk, 0, stream>>>(
                hb, D_, WinH + (size_t)l * 1048576, D_, nullptr,
                xz, 2048, D_, scales + 10 + l, scales + l, scales + 17 + l);

            // u-scale bound from amax(xz) and conv weights (tiny)
            ubound_kernel<<<dim3(1), blk, 0, stream>>>(
                cw_l, cb_l, scales + 17 + l, scales + 20 + l);

            // dbc = u @ Wx.T with conv fused into A-staging
            gemm_conv_t64n<<<dim3(1, rowTiles), blk, 0, stream>>>(
                xz, WxH + (size_t)l * 65536, DI_, cw_l, cb_l, dbc, 64, DI_,
                scales + 20 + l, scales + 7 + l);

            // chunk-parallel scan, delta+conv fused; g -> gbuf
            scan_pass1<<<dim3(CB, DI_ / 256, NCH_), blk, 0, stream>>>(
                xz, dbc, Alog_l, Wdt_l, bdt_l, cw_l, cb_l, Pbuf, Sbuf);
            scan_carry<<<dim3(CB * 64), blk, 0, stream>>>(Pbuf, Sbuf);
            scan_pass3<<<dim3(CB, DI_ / 256, NCH_), blk, 0, stream>>>(
                xz, gbuf, dbc, Alog_l, Wdt_l, bdt_l, cw_l, cb_l, Dp_l,
                Sbuf, scales + 14 + l);

            // h = g @ Wout.T  (A fp32 contiguous, staged-cast) -> hb
            gemm_f32a_t128<0><<<dim3(D_ / 128, rowTiles), blk, 0, stream>>>(
                gbuf, DI_, WoutH + (size_t)l * 524288, DI_, nullptr,
                hb, D_, DI_, scales + 14 + l, scales + 3 + l, scales + 11 + l);
        }

        // out = tanh(h @ Wo.T + bo)
        gemm_f32a_t128<3><<<dim3(DOUT_ / 128, rowTiles), blk, 0, stream>>>(
            hb, D_, WoH, D_, bo, out_c, DOUT_, D_,
            scales + 13, scales + 6, nullptr);
    }
}

// Round 18
// 2581.643 us; speedup vs baseline: 1.2405x; 1.2405x over previous
//
#include <hip/hip_runtime.h>
#include <hip/hip_bf16.h>

#define BB_ 16
#define T_ 2048
#define DIN_ 64
#define D_ 512
#define DI_ 1024
#define N_ 16
#define DC_ 4
#define R_ 32
#define L_ 3
#define DOUT_ 128
#define CL_ 64               // scan chunk length
#define NCH_ (T_ / CL_)      // 32 chunks

typedef __attribute__((ext_vector_type(8))) _Float16 f16x8;
typedef __attribute__((ext_vector_type(4))) float f32x4;

__device__ __forceinline__ float silu_f(float x) { return x / (1.f + __expf(-x)); }

// fast branch-free softplus: log(1+e^t) = max(t,0) + log(1+e^-|t|)
__device__ __forceinline__ float softplus_f(float t) {
    return fmaxf(t, 0.f) + __logf(1.f + __expf(-fabsf(t)));
}

__device__ __forceinline__ unsigned short f2h(float f) {
    union { _Float16 h; unsigned short u; } c;
    c.h = (_Float16)f;   // RNE
    return c.u;
}

// async global->LDS 16B per lane; LDS dest must be lane-linear (tid*16B).
__device__ __forceinline__ void gload_lds16(const unsigned short* g,
                                            unsigned short* l) {
    __builtin_amdgcn_global_load_lds(
        (const __attribute__((address_space(1))) void*)g,
        (__attribute__((address_space(3))) void*)l, 16, 0, 0);
}

// decode scale from amax bits: s = 2^(11 - e), so s*amax lands in [2^11, 2^12)
__device__ __forceinline__ float decode_scale(unsigned int bits) {
    if (bits == 0u) return 1.f;
    const int E = (int)(bits >> 23) & 0xFF;
    return __uint_as_float((unsigned)(265 - E) << 23);
}

__device__ __forceinline__ uint4 pack8(float4 lo, float4 hi, float s) {
    union { uint4 u; unsigned short h[8]; } r;
    r.h[0] = f2h(lo.x * s); r.h[1] = f2h(lo.y * s);
    r.h[2] = f2h(lo.z * s); r.h[3] = f2h(lo.w * s);
    r.h[4] = f2h(hi.x * s); r.h[5] = f2h(hi.y * s);
    r.h[6] = f2h(hi.z * s); r.h[7] = f2h(hi.w * s);
    return r.u;
}

// regions: 0-2 Win[l] (262144 f4), 3-5 Wout[l] (131072), 6 Wo (16384),
// 7-9 Wx[l] (16384). slot == region.
__device__ __forceinline__ const float* wregion(
    int r, const float* Win, const float* Wout, const float* Wx,
    const float* Wo, size_t* n4)
{
    if (r < 3)       { *n4 = 262144; return Win  + (size_t)r * 1048576; }
    else if (r < 6)  { *n4 = 131072; return Wout + (size_t)(r - 3) * 524288; }
    else if (r == 6) { *n4 = 16384;  return Wo; }
    else             { *n4 = 16384;  return Wx  + (size_t)(r - 7) * 65536; }
}

__global__ __launch_bounds__(256) void amax_all(
    const float* __restrict__ Win, const float* __restrict__ Wout,
    const float* __restrict__ Wx, const float* __restrict__ Wo,
    unsigned int* __restrict__ scales)
{
    size_t n4;
    const float* p = wregion(blockIdx.z, Win, Wout, Wx, Wo, &n4);
    float m = 0.f;
    for (size_t i = (size_t)blockIdx.x * 256 + threadIdx.x; i < n4;
         i += (size_t)gridDim.x * 256) {
        const float4 v = ((const float4*)p)[i];
        m = fmaxf(m, fmaxf(fmaxf(fabsf(v.x), fabsf(v.y)),
                           fmaxf(fabsf(v.z), fabsf(v.w))));
    }
#pragma unroll
    for (int off = 32; off; off >>= 1) m = fmaxf(m, __shfl_down(m, off));
    __shared__ float sm[4];
    if ((threadIdx.x & 63) == 0) sm[threadIdx.x >> 6] = m;
    __syncthreads();
    if (threadIdx.x == 0) {
        const float b = fmaxf(fmaxf(sm[0], sm[1]), fmaxf(sm[2], sm[3]));
        atomicMax(scales + blockIdx.z, __float_as_uint(b));
    }
}

__global__ __launch_bounds__(256) void cast_all(
    const float* __restrict__ Win, const float* __restrict__ Wout,
    const float* __restrict__ Wx, const float* __restrict__ Wo,
    unsigned short* __restrict__ WinH, unsigned short* __restrict__ WoutH,
    unsigned short* __restrict__ WxH, unsigned short* __restrict__ WoH,
    const unsigned int* __restrict__ scales)
{
    const int r = blockIdx.z;
    size_t n4;
    const float* p = wregion(r, Win, Wout, Wx, Wo, &n4);
    unsigned short* o;
    if (r < 3)       o = WinH  + (size_t)r * 1048576;
    else if (r < 6)  o = WoutH + (size_t)(r - 3) * 524288;
    else if (r == 6) o = WoH;
    else             o = WxH   + (size_t)(r - 7) * 65536;
    const float s = decode_scale(scales[r]);
    for (size_t i = (size_t)blockIdx.x * 256 + threadIdx.x; i < n4;
         i += (size_t)gridDim.x * 256) {
        const float4 v = ((const float4*)p)[i];
        ((ushort4*)o)[i] = make_ushort4(f2h(v.x * s), f2h(v.y * s),
                                        f2h(v.z * s), f2h(v.w * s));
    }
}

// ------- scaled MFMA GEMM, A fp32 (cast during LDS staging), B f16 --------
// 128x128 tile, BK=32, 4 waves (2x2), per-wave 64x64 = 4x4 frags of 16x16x32.
// A: reg-prefetch pipeline. B: async global_load_lds, double-buffered.
// ACT: 0 = none, 3 = +bias tanh. Output fp32 (+ optional amax).
// NOTE: C must NOT alias A.
template<int ACT>
__global__ __launch_bounds__(256) void gemm_f32a_t128(
    const float* __restrict__ A, int lda,
    const unsigned short* __restrict__ B, int ldb,
    const float* __restrict__ bias,
    float* __restrict__ C, int ldc, int K,
    const unsigned int* __restrict__ sa, const unsigned int* __restrict__ sb,
    unsigned int* __restrict__ oamax)
{
    __shared__ __align__(16) unsigned short As[128 * 32];
    __shared__ __align__(16) unsigned short Bs[2][128 * 32];
    const int tid  = threadIdx.x;
    const int lane = tid & 63;
    const int w    = tid >> 6;
    const int wr   = (w >> 1) << 6;
    const int wc   = (w & 1) << 6;
    const int l15  = lane & 15, l4 = lane >> 4;
    const int row0 = blockIdx.y << 7, col0 = blockIdx.x << 7;
    const int tq   = tid >> 2;
    const int tr   = (tid & 3) << 3;

    const float sA  = decode_scale(*sa);
    const float inv = (1.f / sA) * (1.f / decode_scale(*sb));

    const float* Ar0 = A + (size_t)(row0 + tq) * lda + tr;
    const float* Ar1 = A + (size_t)(row0 + 64 + tq) * lda + tr;
    const unsigned short* Br0 = B + (size_t)(col0 + tq) * ldb + tr;
    const unsigned short* Br1 = B + (size_t)(col0 + 64 + tq) * ldb + tr;

    f32x4 acc[4][4];
#pragma unroll
    for (int m = 0; m < 4; ++m)
#pragma unroll
        for (int n = 0; n < 4; ++n) acc[m][n] = (f32x4){0.f, 0.f, 0.f, 0.f};

    float4 a0lo = *(const float4*)(Ar0), a0hi = *(const float4*)(Ar0 + 4);
    float4 a1lo = *(const float4*)(Ar1), a1hi = *(const float4*)(Ar1 + 4);
    gload_lds16(Br0, &Bs[0][tq * 32 + tr]);
    gload_lds16(Br1, &Bs[0][(64 + tq) * 32 + tr]);

    int cur = 0;
    for (int k0 = 0; k0 < K; k0 += 32) {
        __syncthreads();
        *(uint4*)&As[tq * 32 + tr]        = pack8(a0lo, a0hi, sA);
        *(uint4*)&As[(64 + tq) * 32 + tr] = pack8(a1lo, a1hi, sA);
        __syncthreads();

        if (k0 + 32 < K) {
            gload_lds16(Br0 + k0 + 32, &Bs[cur ^ 1][tq * 32 + tr]);
            gload_lds16(Br1 + k0 + 32, &Bs[cur ^ 1][(64 + tq) * 32 + tr]);
            a0lo = *(const float4*)(Ar0 + k0 + 32);
            a0hi = *(const float4*)(Ar0 + k0 + 36);
            a1lo = *(const float4*)(Ar1 + k0 + 32);
            a1hi = *(const float4*)(Ar1 + k0 + 36);
        }

        f16x8 af[4], bfr[4];
#pragma unroll
        for (int m = 0; m < 4; ++m)
            af[m] = *(const f16x8*)&As[(wr + m * 16 + l15) * 32 + l4 * 8];
#pragma unroll
        for (int n = 0; n < 4; ++n)
            bfr[n] = *(const f16x8*)&Bs[cur][(wc + n * 16 + l15) * 32 + l4 * 8];
#pragma unroll
        for (int m = 0; m < 4; ++m)
#pragma unroll
            for (int n = 0; n < 4; ++n)
                acc[m][n] = __builtin_amdgcn_mfma_f32_16x16x32_f16(
                    af[m], bfr[n], acc[m][n], 0, 0, 0);
        cur ^= 1;
    }

    float am = 0.f;
#pragma unroll
    for (int n = 0; n < 4; ++n) {
        const int col = col0 + wc + n * 16 + l15;
        float bc = 0.f;
        if (ACT == 3) bc = bias[col];
#pragma unroll
        for (int m = 0; m < 4; ++m) {
            const int rowb = row0 + wr + m * 16 + (l4 << 2);
#pragma unroll
            for (int r = 0; r < 4; ++r) {
                float v = acc[m][n][r] * inv;
                if (ACT == 3) v = tanhf(v + bc);
                C[(size_t)(rowb + r) * ldc + col] = v;
                am = fmaxf(am, fabsf(v));
            }
        }
    }
    if (oamax) {
#pragma unroll
        for (int off = 32; off; off >>= 1) am = fmaxf(am, __shfl_down(am, off));
        if (lane == 0) atomicMax(oamax, __float_as_uint(am));
    }
}

// ---- dbc GEMM: A fp32 u (staged cast), B f16 Wx. 128x64 tile, pipelined.
__global__ __launch_bounds__(256) void gemm_f16u_t64n(
    const float* __restrict__ A, int lda,
    const unsigned short* __restrict__ B, int ldb,
    float* __restrict__ C, int ldc, int K,
    const unsigned int* __restrict__ sa, const unsigned int* __restrict__ sb)
{
    __shared__ __align__(16) unsigned short As[128 * 32];
    __shared__ __align__(16) unsigned short Bs[64 * 32];
    const int tid  = threadIdx.x;
    const int lane = tid & 63;
    const int w    = tid >> 6;
    const int l15  = lane & 15, l4 = lane >> 4;
    const int row0 = blockIdx.y << 7;
    const int tq   = tid >> 2;
    const int tr   = (tid & 3) << 3;

    const float sA  = decode_scale(*sa);
    const float inv = (1.f / sA) * (1.f / decode_scale(*sb));

    const float* Ar0 = A + (size_t)(row0 + tq) * lda + tr;
    const float* Ar1 = A + (size_t)(row0 + 64 + tq) * lda + tr;
    const unsigned short* Br = B + (size_t)tq * ldb + tr;   // 64 rows

    f32x4 acc[2][4];
#pragma unroll
    for (int m = 0; m < 2; ++m)
#pragma unroll
        for (int n = 0; n < 4; ++n) acc[m][n] = (f32x4){0.f, 0.f, 0.f, 0.f};

    float4 a0lo = *(const float4*)(Ar0), a0hi = *(const float4*)(Ar0 + 4);
    float4 a1lo = *(const float4*)(Ar1), a1hi = *(const float4*)(Ar1 + 4);
    uint4  bv   = *(const uint4*)(Br);

    for (int k0 = 0; k0 < K; k0 += 32) {
        __syncthreads();
        *(uint4*)&As[tq * 32 + tr]        = pack8(a0lo, a0hi, sA);
        *(uint4*)&As[(64 + tq) * 32 + tr] = pack8(a1lo, a1hi, sA);
        *(uint4*)&Bs[tq * 32 + tr]        = bv;
        __syncthreads();

        if (k0 + 32 < K) {
            a0lo = *(const float4*)(Ar0 + k0 + 32);
            a0hi = *(const float4*)(Ar0 + k0 + 36);
            a1lo = *(const float4*)(Ar1 + k0 + 32);
            a1hi = *(const float4*)(Ar1 + k0 + 36);
            bv   = *(const uint4*)(Br  + k0 + 32);
        }

        f16x8 af[2], bfr[4];
#pragma unroll
        for (int m = 0; m < 2; ++m)
            af[m] = *(const f16x8*)&As[(w * 32 + m * 16 + l15) * 32 + l4 * 8];
#pragma unroll
        for (int n = 0; n < 4; ++n)
            bfr[n] = *(const f16x8*)&Bs[(n * 16 + l15) * 32 + l4 * 8];
#pragma unroll
        for (int m = 0; m < 2; ++m)
#pragma unroll
            for (int n = 0; n < 4; ++n)
                acc[m][n] = __builtin_amdgcn_mfma_f32_16x16x32_f16(
                    af[m], bfr[n], acc[m][n], 0, 0, 0);
    }

#pragma unroll
    for (int n = 0; n < 4; ++n) {
        const int col = n * 16 + l15;
#pragma unroll
        for (int m = 0; m < 2; ++m) {
            const int rowb = row0 + w * 32 + m * 16 + (l4 << 2);
#pragma unroll
            for (int r = 0; r < 4; ++r)
                C[(size_t)(rowb + r) * ldc + col] = acc[m][n][r] * inv;
        }
    }
}

// ---------------- fp32 vector GEMM (input projection, K=64) ----------------
__global__ __launch_bounds__(256) void gemm_in(
    const float* __restrict__ A, int lda,
    const float* __restrict__ B, int ldb,
    const float* __restrict__ bias,
    float* __restrict__ C, int ldc, int K,
    unsigned int* __restrict__ oamax)
{
    __shared__ __align__(16) float As[8][128];
    __shared__ __align__(16) float Bs[8][128];
    const int tid  = threadIdx.x;
    const int row0 = blockIdx.y << 7;
    const int col0 = blockIdx.x << 7;
    const int tx = tid & 15, ty = tid >> 4;

    float acc[8][8];
#pragma unroll
    for (int i = 0; i < 8; ++i)
#pragma unroll
        for (int j = 0; j < 8; ++j) acc[i][j] = 0.f;

    const int arow = tid >> 1;
    const int acol = (tid & 1) << 2;
    const float* Ap = A + (size_t)(row0 + arow) * lda + acol;
    const float* Bp = B + (size_t)(col0 + arow) * ldb + acol;

    for (int k0 = 0; k0 < K; k0 += 8) {
        const float4 av = *(const float4*)(Ap + k0);
        const float4 bv = *(const float4*)(Bp + k0);
        __syncthreads();
        As[acol + 0][arow] = av.x; As[acol + 1][arow] = av.y;
        As[acol + 2][arow] = av.z; As[acol + 3][arow] = av.w;
        Bs[acol + 0][arow] = bv.x; Bs[acol + 1][arow] = bv.y;
        Bs[acol + 2][arow] = bv.z; Bs[acol + 3][arow] = bv.w;
        __syncthreads();
#pragma unroll
        for (int k = 0; k < 8; ++k) {
            float a[8], b[8];
            *(float4*)&a[0] = *(const float4*)&As[k][ty << 3];
            *(float4*)&a[4] = *(const float4*)&As[k][(ty << 3) + 4];
            *(float4*)&b[0] = *(const float4*)&Bs[k][tx << 3];
            *(float4*)&b[4] = *(const float4*)&Bs[k][(tx << 3) + 4];
#pragma unroll
            for (int i = 0; i < 8; ++i)
#pragma unroll
                for (int j = 0; j < 8; ++j)
                    acc[i][j] = fmaf(a[i], b[j], acc[i][j]);
        }
    }

    float bv8[8];
#pragma unroll
    for (int j = 0; j < 8; ++j) bv8[j] = bias[col0 + (tx << 3) + j];

    float am = 0.f;
#pragma unroll
    for (int i = 0; i < 8; ++i) {
        float v[8];
#pragma unroll
        for (int j = 0; j < 8; ++j) {
            v[j] = acc[i][j] + bv8[j];
            am = fmaxf(am, fabsf(v[j]));
        }
        float* Cp = C + (size_t)(row0 + (ty << 3) + i) * ldc + col0 + (tx << 3);
        *(float4*)(Cp)     = make_float4(v[0], v[1], v[2], v[3]);
        *(float4*)(Cp + 4) = make_float4(v[4], v[5], v[6], v[7]);
    }
#pragma unroll
    for (int off = 32; off; off >>= 1) am = fmaxf(am, __shfl_down(am, off));
    if ((tid & 63) == 0) atomicMax(oamax, __float_as_uint(am));
}

// depthwise causal conv (DC=4) + bias + SiLU, float4, grid-stride, fused amax.
__global__ __launch_bounds__(256) void conv_silu_kernel(
    const float* __restrict__ xz, const float* __restrict__ cw,
    const float* __restrict__ cb, float* __restrict__ u,
    size_t total4, unsigned int* __restrict__ uamax)
{
    float am = 0.f;
    for (size_t i = (size_t)blockIdx.x * 256 + threadIdx.x; i < total4;
         i += (size_t)gridDim.x * 256) {
        const size_t e = i * 4;
        const int c = (int)(e & (DI_ - 1));
        const size_t m = e >> 10;
        const int t = (int)(m & (T_ - 1));
        const float* xr = xz + m * 2048 + c;
        const float4 zero = make_float4(0.f, 0.f, 0.f, 0.f);
        const float4 x0 = (t >= 3) ? *(const float4*)(xr - 3 * 2048) : zero;
        const float4 x1 = (t >= 2) ? *(const float4*)(xr - 2 * 2048) : zero;
        const float4 x2 = (t >= 1) ? *(const float4*)(xr - 1 * 2048) : zero;
        const float4 x3 = *(const float4*)(xr);
        const float4 cbv = *(const float4*)(cb + c);
        const float4 w0 = *(const float4*)(cw + (size_t)c * 4);
        const float4 w1 = *(const float4*)(cw + (size_t)(c + 1) * 4);
        const float4 w2 = *(const float4*)(cw + (size_t)(c + 2) * 4);
        const float4 w3 = *(const float4*)(cw + (size_t)(c + 3) * 4);
        float4 r;
        r.x = silu_f(fmaf(x3.x, w0.w, fmaf(x2.x, w0.z, fmaf(x1.x, w0.y, fmaf(x0.x, w0.x, cbv.x)))));
        r.y = silu_f(fmaf(x3.y, w1.w, fmaf(x2.y, w1.z, fmaf(x1.y, w1.y, fmaf(x0.y, w1.x, cbv.y)))));
        r.z = silu_f(fmaf(x3.z, w2.w, fmaf(x2.z, w2.z, fmaf(x1.z, w2.y, fmaf(x0.z, w2.x, cbv.z)))));
        r.w = silu_f(fmaf(x3.w, w3.w, fmaf(x2.w, w3.z, fmaf(x1.w, w3.y, fmaf(x0.w, w3.x, cbv.w)))));
        *(float4*)(u + e) = r;
        am = fmaxf(am, fmaxf(fmaxf(fabsf(r.x), fabsf(r.y)),
                             fmaxf(fabsf(r.z), fabsf(r.w))));
    }
#pragma unroll
    for (int off = 32; off; off >>= 1) am = fmaxf(am, __shfl_down(am, off));
    __shared__ float sm[4];
    if ((threadIdx.x & 63) == 0) sm[threadIdx.x >> 6] = am;
    __syncthreads();
    if (threadIdx.x == 0) {
        const float b = fmaxf(fmaxf(sm[0], sm[1]), fmaxf(sm[2], sm[3]));
        atomicMax(uamax, __float_as_uint(b));
    }
}

// -------- chunk-parallel selective scan, delta fused (3 phases) -----------
// delta inline: dl = softplus(dot32(dbc[m,0:32], Wdt[d,:]) + bdt[d]).
// Carry state compressed: pass1 stores sdl = Sum(dl) per (b,ch,d); carry
// reconstructs p = exp2(sdl*a2[n]) on the fly (identical arithmetic).

__device__ __forceinline__ bool geo_check(const float* a2) {
    bool ok = true;
#pragma unroll
    for (int n = 1; n < N_; ++n)
        ok = ok && (fabsf(a2[n] - a2[0] * (n + 1)) <=
                    1e-5f * fmaxf(1.f, fabsf(a2[n])));
    return ok;
}

__global__ __launch_bounds__(256) void scan_pass1(
    const float* __restrict__ u, const float* __restrict__ dbc,
    const float* __restrict__ A_log_l, const float* __restrict__ Wdt_l,
    const float* __restrict__ bdt_l,
    float* __restrict__ SDL, float* __restrict__ S)
{
    __shared__ __align__(16) float sAll[CL_][64];
    const int tid = threadIdx.x;
    const int b = blockIdx.x, ch = blockIdx.z;
    const int d = (blockIdx.y << 8) + tid;

    float a2[N_], hs[N_];
#pragma unroll
    for (int n = 0; n < N_; ++n) {
        a2[n] = -__expf(A_log_l[d * N_ + n]) * 1.44269504f;
        hs[n] = 0.f;
    }
    const bool geo = geo_check(a2);
    float wdt[32];
#pragma unroll
    for (int k = 0; k < 32; k += 4)
        *(float4*)&wdt[k] = *(const float4*)(Wdt_l + (size_t)d * 32 + k);
    const float bdt_d = bdt_l[d];

    const size_t base64 = ((size_t)b * T_ + (size_t)ch * CL_) * 64;
    float* sflat = &sAll[0][0];
    for (int i = tid; i < CL_ * 64; i += 256) sflat[i] = dbc[base64 + i];
    __syncthreads();

    float sdl = 0.f;
    if (geo) {
        for (int tt = 0; tt < CL_; ++tt) {
            float t = bdt_d;
#pragma unroll
            for (int k = 0; k < 32; k += 4) {
                const float4 dv = *(const float4*)&sAll[tt][k];
                t = fmaf(dv.x, wdt[k + 0], t);
                t = fmaf(dv.y, wdt[k + 1], t);
                t = fmaf(dv.z, wdt[k + 2], t);
                t = fmaf(dv.w, wdt[k + 3], t);
            }
            const float dl = softplus_f(t);
            sdl += dl;
            const size_t m = (size_t)b * T_ + ch * CL_ + tt;
            const float du = dl * u[m * DI_ + d];
            const float r = exp2f(dl * a2[0]);
            float dA = r;
#pragma unroll
            for (int n = 0; n < N_; ++n) {
                hs[n] = fmaf(dA, hs[n], du * sAll[tt][32 + n]);
                dA *= r;
            }
        }
    } else {
        for (int tt = 0; tt < CL_; ++tt) {
            float t = bdt_d;
#pragma unroll
            for (int k = 0; k < 32; k += 4) {
                const float4 dv = *(const float4*)&sAll[tt][k];
                t = fmaf(dv.x, wdt[k + 0], t);
                t = fmaf(dv.y, wdt[k + 1], t);
                t = fmaf(dv.z, wdt[k + 2], t);
                t = fmaf(dv.w, wdt[k + 3], t);
            }
            const float dl = softplus_f(t);
            sdl += dl;
            const size_t m = (size_t)b * T_ + ch * CL_ + tt;
            const float du = dl * u[m * DI_ + d];
#pragma unroll
            for (int n = 0; n < N_; ++n) {
                const float dA = exp2f(dl * a2[n]);
                hs[n] = fmaf(dA, hs[n], du * sAll[tt][32 + n]);
            }
        }
    }
    SDL[(size_t)((b * NCH_ + ch) << 10) + d] = sdl;
#pragma unroll
    for (int n = 0; n < N_; ++n) {
        const size_t idx = (size_t)(((b * NCH_ + ch) * N_ + n) << 10) + d;
        S[idx] = hs[n];
    }
}

// carry: per (b,n,d); p reconstructed from sdl. S[ch] becomes h_init(ch).
__global__ __launch_bounds__(256) void scan_carry(
    const float* __restrict__ SDL, float* __restrict__ S,
    const float* __restrict__ A_log_l)
{
    const size_t gid = (size_t)blockIdx.x * 256 + threadIdx.x;
    const int d = (int)(gid & 1023);
    const int n = (int)((gid >> 10) & 15);
    const int b = (int)(gid >> 14);
    const float a2n = -__expf(A_log_l[d * N_ + n]) * 1.44269504f;
    float hc = 0.f;
    for (int ch = 0; ch < NCH_; ++ch) {
        const float sdl = SDL[(size_t)((b * NCH_ + ch) << 10) + d];
        const float p = exp2f(sdl * a2n);
        const size_t idx = (size_t)(((b * NCH_ + ch) * N_ + n) << 10) + d;
        const float s = S[idx];
        S[idx] = hc;
        hc = fmaf(p, hc, s);
    }
}

__global__ __launch_bounds__(256) void scan_pass3(
    float* __restrict__ xz, const float* __restrict__ u,
    const float* __restrict__ dbc, const float* __restrict__ A_log_l,
    const float* __restrict__ Wdt_l, const float* __restrict__ bdt_l,
    const float* __restrict__ Dp_l, const float* __restrict__ S,
    unsigned int* __restrict__ gmax)
{
    __shared__ __align__(16) float sAll[CL_][64];
    const int tid = threadIdx.x;
    const int b = blockIdx.x, ch = blockIdx.z;
    const int d = (blockIdx.y << 8) + tid;

    float a2[N_], hs[N_];
#pragma unroll
    for (int n = 0; n < N_; ++n) {
        a2[n] = -__expf(A_log_l[d * N_ + n]) * 1.44269504f;
        hs[n] = S[(size_t)(((b * NCH_ + ch) * N_ + n) << 10) + d];
    }
    const bool geo = geo_check(a2);
    float wdt[32];
#pragma unroll
    for (int k = 0; k < 32; k += 4)
        *(float4*)&wdt[k] = *(const float4*)(Wdt_l + (size_t)d * 32 + k);
    const float bdt_d = bdt_l[d];
    const float Dpd = Dp_l[d];

    const size_t base64 = ((size_t)b * T_ + (size_t)ch * CL_) * 64;
    float* sflat = &sAll[0][0];
    for (int i = tid; i < CL_ * 64; i += 256) sflat[i] = dbc[base64 + i];
    __syncthreads();

    float gm = 0.f;
    if (geo) {
        for (int tt = 0; tt < CL_; ++tt) {
            float t = bdt_d;
#pragma unroll
            for (int k = 0; k < 32; k += 4) {
                const float4 dv = *(const float4*)&sAll[tt][k];
                t = fmaf(dv.x, wdt[k + 0], t);
                t = fmaf(dv.y, wdt[k + 1], t);
                t = fmaf(dv.z, wdt[k + 2], t);
                t = fmaf(dv.w, wdt[k + 3], t);
            }
            const float dl = softplus_f(t);
            const size_t m = (size_t)b * T_ + ch * CL_ + tt;
            const float uv = u[m * DI_ + d];
            const float du = dl * uv;
            const float r = exp2f(dl * a2[0]);
            float dA = r;
            float yv = 0.f;
#pragma unroll
            for (int n = 0; n < N_; ++n) {
                hs[n] = fmaf(dA, hs[n], du * sAll[tt][32 + n]);
                yv = fmaf(hs[n], sAll[tt][48 + n], yv);
                dA *= r;
            }
            yv = fmaf(uv, Dpd, yv);
            const float g = yv * silu_f(xz[m * 2048 + DI_ + d]);
            xz[m * 2048 + d] = g;
            gm = fmaxf(gm, fabsf(g));
        }
    } else {
        for (int tt = 0; tt < CL_; ++tt) {
            float t = bdt_d;
#pragma unroll
            for (int k = 0; k < 32; k += 4) {
                const float4 dv = *(const float4*)&sAll[tt][k];
                t = fmaf(dv.x, wdt[k + 0], t);
                t = fmaf(dv.y, wdt[k + 1], t);
                t = fmaf(dv.z, wdt[k + 2], t);
                t = fmaf(dv.w, wdt[k + 3], t);
            }
            const float dl = softplus_f(t);
            const size_t m = (size_t)b * T_ + ch * CL_ + tt;
            const float uv = u[m * DI_ + d];
            const float du = dl * uv;
            float yv = 0.f;
#pragma unroll
            for (int n = 0; n < N_; ++n) {
                const float dA = exp2f(dl * a2[n]);
                hs[n] = fmaf(dA, hs[n], du * sAll[tt][32 + n]);
                yv = fmaf(hs[n], sAll[tt][48 + n], yv);
            }
            yv = fmaf(uv, Dpd, yv);
            const float g = yv * silu_f(xz[m * 2048 + DI_ + d]);
            xz[m * 2048 + d] = g;
            gm = fmaxf(gm, fabsf(g));
        }
    }
#pragma unroll
    for (int off = 32; off; off >>= 1) gm = fmaxf(gm, __shfl_down(gm, off));
    if ((tid & 63) == 0) atomicMax(gmax, __float_as_uint(gm));
}

extern "C" void kernel_launch(void* const* d_in, const int* in_sizes, int n_in,
                              void* d_out, int out_size, void* d_ws, size_t ws_size,
                              hipStream_t stream) {
    const float* x     = (const float*)d_in[0];
    const float* Wi    = (const float*)d_in[1];
    const float* bi    = (const float*)d_in[2];
    const float* Win   = (const float*)d_in[3];
    const float* convw = (const float*)d_in[4];
    const float* convb = (const float*)d_in[5];
    const float* Wx    = (const float*)d_in[6];
    const float* Wdt   = (const float*)d_in[7];
    const float* bdt   = (const float*)d_in[8];
    const float* A_log = (const float*)d_in[9];
    const float* Dp    = (const float*)d_in[10];
    const float* Wout  = (const float*)d_in[11];
    const float* Wo    = (const float*)d_in[12];
    const float* bo    = (const float*)d_in[13];
    float* out = (float*)d_out;

    // Per-row f32: xz 2048 + u 1024 + dbc 64 + hPS 512 (h | SDL+S) = 3648.
    const size_t rowf = 3648;
    const size_t wextra =
        (3 * 1048576 + 3 * 524288 + 65536 + 3 * 65536) / 2 + 32;
    int CB = BB_;
    while (CB > 1 && ((size_t)CB * T_ * rowf + wextra) * sizeof(float) > ws_size) CB >>= 1;
    const size_t Mc = (size_t)CB * T_;

    const dim3 blk(256);
    const int rowTiles = (int)(Mc / 128);

    float* ws   = (float*)d_ws;
    float* xz   = ws;                    // Mc*2048 (xin/g | z)
    float* u    = xz + Mc * 2048;        // Mc*1024
    float* dbc  = u  + Mc * 1024;        // Mc*64
    float* hPS  = dbc + Mc * 64;         // Mc*512: h (ld 512) / SDL+S
    float* hb   = hPS;
    float* Sdl  = hPS;                               // Mc*16 floats
    float* Sbuf = hPS + Mc * 16;                     // Mc*256 floats
    unsigned short* WinH  = (unsigned short*)(hPS + Mc * 512);
    unsigned short* WoutH = WinH + 3 * 1048576;
    unsigned short* WoH   = WoutH + 3 * 524288;
    unsigned short* WxH   = WoH + 65536;
    unsigned int* scales  = (unsigned int*)(WxH + 3 * 65536);
    // slots: 0-2 Win, 3-5 Wout, 6 Wo, 7-9 Wx,
    //        10..13 h[0..3], 14-16 g[l], 17-19 u[l]

    hipMemsetAsync(scales, 0, 32 * sizeof(unsigned int), stream);

    amax_all<<<dim3(128, 1, 10), blk, 0, stream>>>(Win, Wout, Wx, Wo, scales);
    cast_all<<<dim3(64, 1, 10), blk, 0, stream>>>(
        Win, Wout, Wx, Wo, WinH, WoutH, WxH, WoH, scales);

    for (int c = 0; c < BB_ / CB; ++c) {
        const float* x_c = x + (size_t)c * Mc * DIN_;
        float* out_c     = out + (size_t)c * Mc * DOUT_;

        hipMemsetAsync(scales + 10, 0, 10 * sizeof(unsigned int), stream);

        // h = x @ Wi.T + bi  (fp32, K=64) -> hb (ld 512), amax -> h[0]
        gemm_in<<<dim3(D_ / 128, rowTiles), blk, 0, stream>>>(
            x_c, DIN_, Wi, DIN_, bi, hb, D_, DIN_, scales + 10);

        for (int l = 0; l < L_; ++l) {
            const float* cw_l   = convw + (size_t)l * DI_ * DC_;
            const float* cb_l   = convb + (size_t)l * DI_;
            const float* Wdt_l  = Wdt  + (size_t)l * DI_ * R_;
            const float* bdt_l  = bdt  + (size_t)l * DI_;
            const float* Alog_l = A_log + (size_t)l * DI_ * N_;
            const float* Dp_l   = Dp   + (size_t)l * DI_;

            // xz = h @ Win.T  (A fp32 staged-cast, B async-lds, pipelined)
            gemm_f32a_t128<0><<<dim3(2048 / 128, rowTiles), blk, 0, stream>>>(
                hb, D_, WinH + (size_t)l * 1048576, D_, nullptr,
                xz, 2048, D_, scales + 10 + l, scales + l, nullptr);

            // u = silu(causal_dwconv(xin) + cb), fused u amax
            conv_silu_kernel<<<dim3(2048), blk, 0, stream>>>(
                xz, cw_l, cb_l, u, Mc * DI_ / 4, scales + 17 + l);

            // dbc = u @ Wx.T  (f16 MFMA 128x64)
            gemm_f16u_t64n<<<dim3(1, rowTiles), blk, 0, stream>>>(
                u, DI_, WxH + (size_t)l * 65536, DI_, dbc, 64, DI_,
                scales + 17 + l, scales + 7 + l);

            // chunk-parallel scan with fused delta; g -> xz[:, :1024]
            scan_pass1<<<dim3(CB, DI_ / 256, NCH_), blk, 0, stream>>>(
                u, dbc, Alog_l, Wdt_l, bdt_l, Sdl, Sbuf);
            scan_carry<<<dim3(CB * 64), blk, 0, stream>>>(Sdl, Sbuf, Alog_l);
            scan_pass3<<<dim3(CB, DI_ / 256, NCH_), blk, 0, stream>>>(
                xz, u, dbc, Alog_l, Wdt_l, bdt_l, Dp_l, Sbuf, scales + 14 + l);

            // h = g @ Wout.T  (A fp32 staged-cast) -> hb (SDL/S dead)
            gemm_f32a_t128<0><<<dim3(D_ / 128, rowTiles), blk, 0, stream>>>(
                xz, 2048, WoutH + (size_t)l * 524288, DI_, nullptr,
                hb, D_, DI_, scales + 14 + l, scales + 3 + l, scales + 11 + l);
        }

        // out = tanh(h @ Wo.T + bo)
        gemm_f32a_t128<3><<<dim3(DOUT_ / 128, rowTiles), blk, 0, stream>>>(
            hb, D_, WoH, D_, bo, out_c, DOUT_, D_,
            scales + 13, scales + 6, nullptr);
    }
}